// Round 6
// baseline (172.308 us; speedup 1.0000x reference)
//
#include <hip/hip_runtime.h>
#include <hip/hip_bf16.h>

// Shapes (fixed by the reference)
#define NB 8
#define ND 512
#define NL 2048
#define NH 8
#define NDH 64
#define VROWS 72   // V head rows: 64 V rows (+8 unused pad rows for stride)

typedef __attribute__((ext_vector_type(8))) short bf16x8;
typedef __attribute__((ext_vector_type(4))) float f32x4;
typedef __attribute__((ext_vector_type(4))) unsigned int u32x4;

__device__ __forceinline__ unsigned short f2bf(float x) {
    return (unsigned short)((__float_as_uint(x) + 0x8000u) >> 16);
}

__device__ __forceinline__ float exp2_fast(float x) {
#if __has_builtin(__builtin_amdgcn_exp2f)
    return __builtin_amdgcn_exp2f(x);
#else
    return exp2f(x);
#endif
}

// pack bf16(a) | bf16(b)<<16
__device__ __forceinline__ unsigned int pack_bf16(float a, float b) {
#if __has_builtin(__builtin_amdgcn_cvt_pk_bf16_f32)
    auto r = __builtin_amdgcn_cvt_pk_bf16_f32(a, b);
    unsigned int u;
    __builtin_memcpy(&u, &r, 4);
    return u;
#else
    unsigned int ua = __float_as_uint(a) + 0x8000u;
    unsigned int ub = __float_as_uint(b) + 0x8000u;
    return __builtin_amdgcn_perm(ub, ua, 0x07060302u);
#endif
}

// key permutation within a 64-tile (PV B-operand == S^T C-layout)
__device__ __forceinline__ int perm64(int k) {
    return (k & 32) | ((k & 12) << 1) | ((k & 16) >> 2) | (k & 3);
}

// async global->LDS, 16 B per lane; lds base wave-uniform, lane i -> lds+i*16.
__device__ __forceinline__ void async16(void* lds, const void* g) {
    __builtin_amdgcn_global_load_lds(
        (const __attribute__((address_space(1))) unsigned int*)g,
        (__attribute__((address_space(3))) unsigned int*)lds, 16, 0, 0);
}

// ---------------------------------------------------------------------------
// prep: fused convert_xt (blocks 0..2047) + convert_w (2048..2431) +
// per-(batch,head) mask compaction (2432..2495).  (Identical to R4/R5.)
// ---------------------------------------------------------------------------
__global__ __launch_bounds__(256) void prep(
    const float* __restrict__ qin,
    const float* __restrict__ w_mem, const float* __restrict__ w_q,
    const int* __restrict__ maskp,
    unsigned short* __restrict__ Xt, unsigned short* __restrict__ Wc,
    unsigned short* __restrict__ Vt, unsigned short* __restrict__ Kh,
    int* __restrict__ cmap, int* __restrict__ ntile, int* __restrict__ nvalid)
{
    const int bid = blockIdx.x;
    const int t = threadIdx.x;
    if (bid < 2048) {
        __shared__ __align__(16) unsigned short T[64][72];
        const int l0 = (bid & 31) * 64, d0 = ((bid >> 5) & 7) * 64, b = bid >> 8;
        const float* X = qin + ((size_t)b * ND + d0) * NL + l0;
        #pragma unroll
        for (int i = 0; i < 4; ++i) {
            int e = t + i * 256;
            int d = e >> 4, l4 = (e & 15) * 4;
            float4 v = *(const float4*)(X + (size_t)d * NL + l4);
            T[l4 + 0][d] = f2bf(v.x);
            T[l4 + 1][d] = f2bf(v.y);
            T[l4 + 2][d] = f2bf(v.z);
            T[l4 + 3][d] = f2bf(v.w);
        }
        __syncthreads();
        #pragma unroll
        for (int i = 0; i < 2; ++i) {
            int e = t + i * 256;
            int row = e >> 3, c8 = (e & 7) * 8;
            *(bf16x8*)(Xt + ((size_t)b * NL + l0 + row) * ND + d0 + c8) =
                *(const bf16x8*)&T[row][c8];
        }
    } else if (bid < 2432) {
        int idx = ((bid - 2048) * 256 + t) * 8;
        int o = idx >> 9, k = idx & 511;
        const float* src;
        float sc;
        if (o < 1024) { src = w_mem + (size_t)o * ND + k; sc = 1.0f; }
        else          { src = w_q + (size_t)(o - 1024) * ND + k;
                        sc = 0.125f * 1.4426950408889634f; }
        float4 f0 = *(const float4*)src;
        float4 f1 = *(const float4*)(src + 4);
        ushort4 p0 = { f2bf(f0.x * sc), f2bf(f0.y * sc), f2bf(f0.z * sc), f2bf(f0.w * sc) };
        ushort4 p1 = { f2bf(f1.x * sc), f2bf(f1.y * sc), f2bf(f1.z * sc), f2bf(f1.w * sc) };
        *(ushort4*)(Wc + idx) = p0;
        *(ushort4*)(Wc + idx + 4) = p1;
    } else {
        // ---- per-(batch,head) mask compaction ----
        __shared__ int wsum[4];
        const int sb = bid - 2432;
        const int b = sb >> 3, hh = sb & 7;
        const int lane = t & 63, wv = t >> 6;
        int4 ma = *(const int4*)&maskp[b * NL + t * 8];
        int4 mb = *(const int4*)&maskp[b * NL + t * 8 + 4];
        int m[8] = {ma.x, ma.y, ma.z, ma.w, mb.x, mb.y, mb.z, mb.w};
        int loc = 0;
        #pragma unroll
        for (int i = 0; i < 8; ++i) loc += m[i];
        int sc = loc;                         // wave inclusive scan
        #pragma unroll
        for (int off = 1; off < 64; off <<= 1) {
            int v = __shfl_up(sc, off);
            if (lane >= off) sc += v;
        }
        if (lane == 63) wsum[wv] = sc;
        __syncthreads();
        int wbase = 0;
        #pragma unroll
        for (int i = 0; i < 4; ++i) if (i < wv) wbase += wsum[i];
        int j = wbase + sc - loc;             // exclusive prefix for this group
        if (hh == 0) {
            int jj = j;
            #pragma unroll
            for (int i = 0; i < 8; ++i) {
                cmap[b * NL + t * 8 + i] = m[i] ? jj : -1;
                jj += m[i];
            }
        }
        const int nb = wsum[0] + wsum[1] + wsum[2] + wsum[3];
        const int Nt = (nb + 63) & ~63;
        if (hh == 0 && t == 0) { ntile[b] = Nt >> 6; nvalid[b] = nb; }
        const int pad = Nt - nb;
        for (int e = t; e < pad * 64; e += 256) {
            int jj = nb + (e >> 6), dd = e & 63;
            int slot = (jj & ~63) | perm64(jj & 63);
            Vt[(((size_t)(b * NH + hh)) * VROWS + dd) * NL + slot] = 0;
            Kh[(((size_t)(b * NH + hh)) * NL + jj) * NDH + dd] = 0;
        }
    }
}

// ---------------------------------------------------------------------------
// proj_mfma: C[o][l] = sum_k Wc[o][k] * Xt[b][l][k].
// EXACT R0/R4/R5 version. Session-noise probe: identical code measured
// 48.9 / 62.0 / 50.4 us across sessions -- deltas <20% are unmeasurable.
// ---------------------------------------------------------------------------
__global__ __launch_bounds__(256, 3) void proj_mfma(
    const unsigned short* __restrict__ Wc,
    const unsigned short* __restrict__ Xt,
    const int* __restrict__ cmap,
    unsigned short* __restrict__ Kh,
    unsigned short* __restrict__ Qh,
    unsigned short* __restrict__ Vt)
{
    __shared__ __align__(16) unsigned short As[128 * 64];
    __shared__ __align__(16) unsigned short Bs[128 * 64];

    const int b  = blockIdx.z;
    const int m0 = blockIdx.y * 128;
    const int n0 = blockIdx.x * 128;
    const int t  = threadIdx.x;
    const int w = t >> 6, lane = t & 63, quad = lane >> 4, lq = lane & 15;
    const int wo = (w >> 1) * 64, wl = (w & 1) * 64;
    const int lr = lane >> 3;
    const int cbsw = (lane & 7) ^ lr;
    const bool isV = (m0 >= 512) && (m0 < 1024);
    const f32x4 z4 = {0.f, 0.f, 0.f, 0.f};
    const int sw[2] = {(quad ^ (lq & 7)) * 8, ((4 + quad) ^ (lq & 7)) * 8};

    f32x4 acc[4][4];
    #pragma unroll
    for (int im = 0; im < 4; ++im)
        #pragma unroll
        for (int in = 0; in < 4; ++in) acc[im][in] = z4;

    if (!isV) {
        for (int k0 = 0; k0 < ND; k0 += 64) {
            __syncthreads();
            #pragma unroll 2
            for (int i = w; i < 32; i += 4) {
                if (i < 16) {
                    int R = i * 8;
                    async16(&As[R * 64],
                            Wc + (size_t)(m0 + R + lr) * ND + k0 + cbsw * 8);
                } else {
                    int R = (i - 16) * 8;
                    async16(&Bs[R * 64],
                            Xt + ((size_t)b * NL + n0 + R + lr) * ND + k0 + cbsw * 8);
                }
            }
            __syncthreads();
            #pragma unroll
            for (int ks = 0; ks < 2; ++ks) {
                bf16x8 af[4], bfr[4];
                #pragma unroll
                for (int im = 0; im < 4; ++im)
                    af[im] = *(const bf16x8*)&As[(wo + im * 16 + lq) * 64 + sw[ks]];
                #pragma unroll
                for (int in = 0; in < 4; ++in)
                    bfr[in] = *(const bf16x8*)&Bs[(wl + in * 16 + lq) * 64 + sw[ks]];
                #pragma unroll
                for (int im = 0; im < 4; ++im)
                    #pragma unroll
                    for (int in = 0; in < 4; ++in)
                        acc[im][in] = __builtin_amdgcn_mfma_f32_16x16x32_bf16(
                            af[im], bfr[in], acc[im][in], 0, 0, 0);
            }
        }
        if (m0 < 512) {
            // K region: compacted rows
            int j[4];
            #pragma unroll
            for (int in = 0; in < 4; ++in)
                j[in] = cmap[b * NL + n0 + wl + in * 16 + lq];
            #pragma unroll
            for (int im = 0; im < 4; ++im) {
                int o  = (m0 + wo + im * 16 + quad * 4) & 511;
                int hh = o >> 6, dh = o & 63;
                #pragma unroll
                for (int in = 0; in < 4; ++in) {
                    if (j[in] >= 0) {
                        ushort4 pk = { f2bf(acc[im][in][0]), f2bf(acc[im][in][1]),
                                       f2bf(acc[im][in][2]), f2bf(acc[im][in][3]) };
                        *(ushort4*)&Kh[(((size_t)b * NH + hh) * NL + j[in]) * NDH + dh] = pk;
                    }
                }
            }
        } else {
            // Q region: unchanged
            #pragma unroll
            for (int im = 0; im < 4; ++im) {
                int o  = (m0 + wo + im * 16 + quad * 4) & 511;
                int hh = o >> 6, dh = o & 63;
                #pragma unroll
                for (int in = 0; in < 4; ++in) {
                    int l = n0 + wl + in * 16 + lq;
                    ushort4 pk = { f2bf(acc[im][in][0]), f2bf(acc[im][in][1]),
                                   f2bf(acc[im][in][2]), f2bf(acc[im][in][3]) };
                    *(ushort4*)&Qh[(((size_t)b * NH + hh) * NL + l) * NDH + dh] = pk;
                }
            }
        }
    } else {
        for (int k0 = 0; k0 < ND; k0 += 64) {
            __syncthreads();
            #pragma unroll 2
            for (int i = w; i < 32; i += 4) {
                if (i < 16) {
                    int R = i * 8;
                    async16(&As[R * 64],
                            Wc + (size_t)(m0 + R + lr) * ND + k0 + cbsw * 8);
                } else {
                    int R = (i - 16) * 8;
                    async16(&Bs[R * 64],
                            Xt + ((size_t)b * NL + n0 + R + lr) * ND + k0 + cbsw * 8);
                }
            }
            __syncthreads();
            #pragma unroll
            for (int ks = 0; ks < 2; ++ks) {
                bf16x8 af[4], bfr[4];
                #pragma unroll
                for (int im = 0; im < 4; ++im)
                    af[im] = *(const bf16x8*)&As[(wo + im * 16 + lq) * 64 + sw[ks]];
                #pragma unroll
                for (int in = 0; in < 4; ++in)
                    bfr[in] = *(const bf16x8*)&Bs[(wl + in * 16 + lq) * 64 + sw[ks]];
                // swapped: acc[im = l-subtile][in = dh-subtile]
                #pragma unroll
                for (int im = 0; im < 4; ++im)
                    #pragma unroll
                    for (int in = 0; in < 4; ++in)
                        acc[im][in] = __builtin_amdgcn_mfma_f32_16x16x32_bf16(
                            bfr[im], af[in], acc[im][in], 0, 0, 0);
            }
        }
        // V region: compacted + key-permuted scalar scatter
        #pragma unroll
        for (int im = 0; im < 4; ++im) {
            int l4 = n0 + wl + im * 16 + quad * 4;      // 4 consecutive l
            int4 j4 = *(const int4*)&cmap[b * NL + l4];
            int jj[4] = {j4.x, j4.y, j4.z, j4.w};
            int slot[4];
            #pragma unroll
            for (int r = 0; r < 4; ++r)
                slot[r] = (jj[r] & ~63) | perm64(jj[r] & 63);
            #pragma unroll
            for (int in = 0; in < 4; ++in) {
                int o  = m0 - 512 + wo + in * 16 + lq;  // 0..511
                int hh = o >> 6, dd = o & 63;
                const size_t rowbase = (((size_t)(b * NH + hh)) * VROWS + dd) * NL;
                #pragma unroll
                for (int r = 0; r < 4; ++r)
                    if (jj[r] >= 0)
                        Vt[rowbase + slot[r]] = f2bf(acc[im][in][r]);
            }
        }
    }
}

// ---------------------------------------------------------------------------
// attn_mfma: 256-thread blocks (4 waves x 64 q-rows = 256-row q-tile),
// grid 512 = 2 blocks/CU. NEW vs R5: q-rows/wave 32 -> 64 (ni = 0..3),
// waves/block 8 -> 4. Each kf/vf LDS read now feeds 4 MFMAs instead of 2,
// HALVING per-CU ds_read_b128 cycles -- the dominant attn cost (~21 us
// chip-wide at R5 geometry). MFMA/VALU totals unchanged; KVBLK=128
// mega-tiles and f32 pre-pack lsum retained. QK is computed per-ks phase
// (sacc[2][4] live, not [4][4]) to keep VGPRs ~180. Per-accumulator MFMA
// order identical to R5 => bit-identical numerics.
// ---------------------------------------------------------------------------
__global__ __launch_bounds__(256, 2) void attn_mfma(
    const unsigned short* __restrict__ Qh,
    const unsigned short* __restrict__ Kh,
    const unsigned short* __restrict__ Vt,
    const int* __restrict__ ntilep,
    const int* __restrict__ nvalidp,
    float* __restrict__ out)
{
    __shared__ __align__(16) unsigned short Ks2[2][2 * 64 * 64];  // 2 x 16 KB
    __shared__ __align__(16) unsigned short Vs2[2][2 * 64 * 64];  // 2 x 16 KB

    const int id = blockIdx.x;
    const int h  = id & 7;                 // XCD swizzle: same h -> same XCD
    const int b  = (id >> 3) & 7;
    const int q0 = (id >> 6) * 256;
    const int t = threadIdx.x;             // 0..255
    const int w = t >> 6;                  // 0..3
    const int lane = t & 63, quad = lane >> 4, lq = lane & 15;
    const int lr = lane >> 3;
    const int cbsw = (lane & 7) ^ lr;
    const f32x4 z4 = {0.f, 0.f, 0.f, 0.f};

    const unsigned short* Qg = Qh + ((size_t)(b * NH + h)) * NL * NDH;
    const unsigned short* Kg = Kh + ((size_t)(b * NH + h)) * NL * NDH;
    const unsigned short* Vg = Vt + ((size_t)(b * NH + h)) * VROWS * NL;
    const int ntiles = ntilep[b];

    const int sw0 = (quad ^ (lq & 7)) * 8;
    const int sw1 = ((4 + quad) ^ (lq & 7)) * 8;

    // wave w stages K rows 16w..16w+15 and V rows 16w..16w+15 of each half
    const unsigned short* kgp  = Kg + (size_t)(w * 16 + lr) * NDH + cbsw * 8;
    const unsigned short* kgp8 = kgp + (size_t)8 * NDH;
    const unsigned short* vgp  = Vg + (size_t)(w * 16 + lr) * NL + cbsw * 8;
    const unsigned short* vgp8 = vgp + (size_t)8 * NL;

    // stage a 128-key mega-tile (halves at +0 and +4096 ushorts)
    auto stage128 = [&](unsigned short* Kd, unsigned short* Vd, int kn) {
        async16(Kd + w * 1024,              kgp  + (size_t)kn * NDH);
        async16(Kd + w * 1024 + 512,        kgp8 + (size_t)kn * NDH);
        async16(Kd + 4096 + w * 1024,       kgp  + (size_t)(kn + 64) * NDH);
        async16(Kd + 4096 + w * 1024 + 512, kgp8 + (size_t)(kn + 64) * NDH);
        async16(Vd + w * 1024,              vgp  + kn);
        async16(Vd + w * 1024 + 512,        vgp8 + kn);
        async16(Vd + 4096 + w * 1024,       vgp  + kn + 64);
        async16(Vd + 4096 + w * 1024 + 512, vgp8 + kn + 64);
    };

    // ---- stage mega-tile 0; Q fragments straight to registers meanwhile ----
    stage128(Ks2[0], Vs2[0], 0);

    bf16x8 qf[4][2];
    #pragma unroll
    for (int ni = 0; ni < 4; ++ni)
        #pragma unroll
        for (int ks = 0; ks < 2; ++ks)
            qf[ni][ks] = *(const bf16x8*)
                &Qg[(size_t)(q0 + w * 64 + ni * 16 + lq) * NDH + ks * 32 + quad * 8];

    f32x4 oacc[4][4];
    #pragma unroll
    for (int dm = 0; dm < 4; ++dm)
        #pragma unroll
        for (int ni = 0; ni < 4; ++ni) oacc[dm][ni] = z4;
    float ls[4] = {0.f, 0.f, 0.f, 0.f};   // per-lane partial row-sums of p

    // one 64-key sub-body on (KsB, VsB)
    auto sub = [&](const unsigned short* KsB, const unsigned short* VsB) {
        const unsigned short* kb0 = KsB + lq * 64 + sw0;
        const unsigned short* kb1 = KsB + lq * 64 + sw1;
        const unsigned short* vb0 = VsB + lq * 64 + sw0;
        const unsigned short* vb1 = VsB + lq * 64 + sw1;

        #pragma unroll
        for (int ks = 0; ks < 2; ++ks) {
            // ---- S^T = K Q^T for this ks-half (log2 units) ----
            f32x4 sacc[2][4];
            #pragma unroll
            for (int half = 0; half < 2; ++half) {
                const int mi = ks * 2 + half;
                bf16x8 kf0 = *(const bf16x8*)&kb0[mi * 1024];
                #pragma unroll
                for (int ni = 0; ni < 4; ++ni)
                    sacc[half][ni] = __builtin_amdgcn_mfma_f32_16x16x32_bf16(
                        kf0, qf[ni][0], z4, 0, 0, 0);
                bf16x8 kf1 = *(const bf16x8*)&kb1[mi * 1024];
                #pragma unroll
                for (int ni = 0; ni < 4; ++ni)
                    sacc[half][ni] = __builtin_amdgcn_mfma_f32_16x16x32_bf16(
                        kf1, qf[ni][1], sacc[half][ni], 0, 0, 0);
            }
            // ---- p = exp2(s), f32 presum, pack ----
            u32x4 pfu[4];
            #pragma unroll
            for (int half = 0; half < 2; ++half) {
                const int jp = half * 2;
                #pragma unroll
                for (int ni = 0; ni < 4; ++ni) {
                    float e0 = exp2_fast(sacc[half][ni][0]);
                    float e1 = exp2_fast(sacc[half][ni][1]);
                    float e2 = exp2_fast(sacc[half][ni][2]);
                    float e3 = exp2_fast(sacc[half][ni][3]);
                    ls[ni] += (e0 + e1) + (e2 + e3);
                    pfu[ni][jp + 0] = pack_bf16(e0, e1);
                    pfu[ni][jp + 1] = pack_bf16(e2, e3);
                }
            }
            // ---- PV MFMA ----
            const unsigned short* vb = ks ? vb1 : vb0;
            #pragma unroll
            for (int dm = 0; dm < 4; ++dm) {
                bf16x8 vf = *(const bf16x8*)&vb[dm * 1024];
                #pragma unroll
                for (int ni = 0; ni < 4; ++ni)
                    oacc[dm][ni] = __builtin_amdgcn_mfma_f32_16x16x32_bf16(
                        vf, __builtin_bit_cast(bf16x8, pfu[ni]), oacc[dm][ni], 0, 0, 0);
            }
        }
    };

    const int npairs = ntiles >> 1, odd = ntiles & 1;
    int p = 0;
    #pragma unroll 1
    for (; p + 1 < npairs; ++p) {
        const int cb = p & 1;
        __syncthreads();          // drains DMA for buf cb; frees buf cb^1
        stage128(Ks2[cb ^ 1], Vs2[cb ^ 1], (p + 1) * 128);
        sub(Ks2[cb], Vs2[cb]);
        sub(Ks2[cb] + 4096, Vs2[cb] + 4096);
    }
    if (npairs > 0) {             // last full pair; prefetch odd tail if any
        const int cb = p & 1;
        __syncthreads();
        if (odd) stage128(Ks2[cb ^ 1], Vs2[cb ^ 1], npairs * 128);
        sub(Ks2[cb], Vs2[cb]);
        sub(Ks2[cb] + 4096, Vs2[cb] + 4096);
        ++p;
    }
    if (odd) {                    // tail: half 0 of the last-staged buffer
        const int cb = p & 1;
        __syncthreads();
        sub(Ks2[cb], Vs2[cb]);
    }

    // ---- epilogue: reduce ls across the 4 quads; subtract exact pad ----
    const float padc = (float)(ntiles * 64 - nvalidp[b]);
    float inv[4];
    #pragma unroll
    for (int ni = 0; ni < 4; ++ni) {
        float s = ls[ni];
        s += __shfl_xor(s, 16);
        s += __shfl_xor(s, 32);
        inv[ni] = 1.0f / (s - padc);
    }

    #pragma unroll
    for (int dm = 0; dm < 4; ++dm)
        #pragma unroll
        for (int ni = 0; ni < 4; ++ni)
            #pragma unroll
            for (int r = 0; r < 4; ++r) {
                int dh = dm * 16 + quad * 4 + r;
                int l  = q0 + w * 64 + ni * 16 + lq;
                out[((size_t)b * ND + h * NDH + dh) * NL + l] =
                    oacc[dm][ni][r] * inv[ni];
            }
}

extern "C" void kernel_launch(void* const* d_in, const int* in_sizes, int n_in,
                              void* d_out, int out_size, void* d_ws, size_t ws_size,
                              hipStream_t stream) {
    const float* queries = (const float*)d_in[0];
    const int*   maskp   = (const int*)d_in[1];
    const float* w_mem   = (const float*)d_in[2];
    const float* w_q     = (const float*)d_in[3];
    float* out = (float*)d_out;

    const size_t headElems  = (size_t)NB * NH * NL * NDH;    // 8.39M
    const size_t vElems     = (size_t)NB * NH * VROWS * NL;  // 9.44M
    unsigned short* Kh = (unsigned short*)d_ws;
    unsigned short* Vt = Kh + headElems;
    unsigned short* Qh = Vt + vElems;
    unsigned short* Wc = Qh + headElems;                     // 1536*512
    unsigned short* Xt = Wc + (size_t)1536 * ND;             // 8*2048*512
    int* cmap   = (int*)(Xt + (size_t)NB * NL * ND);         // 8*2048 ints
    int* ntile  = cmap + NB * NL;                            // 8 ints
    int* nvalid = ntile + NB;                                // 8 ints
    // total ws use: ~71 MB

    prep<<<2496, 256, 0, stream>>>(queries, w_mem, w_q, maskp,
                                   Xt, Wc, Vt, Kh, cmap, ntile, nvalid);

    dim3 g1(NL / 128, 1536 / 128, NB); // (16, 12, 8)
    proj_mfma<<<g1, 256, 0, stream>>>(Wc, Xt, cmap, Kh, Qh, Vt);

    attn_mfma<<<512, 256, 0, stream>>>(Qh, Kh, Vt, ntile, nvalid, out);
}

// Round 7
// 169.625 us; speedup vs baseline: 1.0158x; 1.0158x over previous
//
#include <hip/hip_runtime.h>
#include <hip/hip_bf16.h>

// Shapes (fixed by the reference)
#define NB 8
#define ND 512
#define NL 2048
#define NH 8
#define NDH 64
#define VROWS 72   // V head rows: 64 V rows (+8 unused pad rows for stride)

typedef __attribute__((ext_vector_type(8))) short bf16x8;
typedef __attribute__((ext_vector_type(4))) float f32x4;
typedef __attribute__((ext_vector_type(4))) unsigned int u32x4;

__device__ __forceinline__ unsigned short f2bf(float x) {
    return (unsigned short)((__float_as_uint(x) + 0x8000u) >> 16);
}

__device__ __forceinline__ float exp2_fast(float x) {
#if __has_builtin(__builtin_amdgcn_exp2f)
    return __builtin_amdgcn_exp2f(x);
#else
    return exp2f(x);
#endif
}

// pack bf16(a) | bf16(b)<<16
__device__ __forceinline__ unsigned int pack_bf16(float a, float b) {
#if __has_builtin(__builtin_amdgcn_cvt_pk_bf16_f32)
    auto r = __builtin_amdgcn_cvt_pk_bf16_f32(a, b);
    unsigned int u;
    __builtin_memcpy(&u, &r, 4);
    return u;
#else
    unsigned int ua = __float_as_uint(a) + 0x8000u;
    unsigned int ub = __float_as_uint(b) + 0x8000u;
    return __builtin_amdgcn_perm(ub, ua, 0x07060302u);
#endif
}

// key permutation within a 64-tile (PV B-operand == S^T C-layout)
__device__ __forceinline__ int perm64(int k) {
    return (k & 32) | ((k & 12) << 1) | ((k & 16) >> 2) | (k & 3);
}

// async global->LDS, 16 B per lane; lds base wave-uniform, lane i -> lds+i*16.
__device__ __forceinline__ void async16(void* lds, const void* g) {
    __builtin_amdgcn_global_load_lds(
        (const __attribute__((address_space(1))) unsigned int*)g,
        (__attribute__((address_space(3))) unsigned int*)lds, 16, 0, 0);
}

// ---------------------------------------------------------------------------
// prep: fused convert_xt (blocks 0..2047) + convert_w (2048..2431) +
// per-(batch,head) mask compaction (2432..2495).  (Identical to R4/R5/R6.)
// ---------------------------------------------------------------------------
__global__ __launch_bounds__(256) void prep(
    const float* __restrict__ qin,
    const float* __restrict__ w_mem, const float* __restrict__ w_q,
    const int* __restrict__ maskp,
    unsigned short* __restrict__ Xt, unsigned short* __restrict__ Wc,
    unsigned short* __restrict__ Vt, unsigned short* __restrict__ Kh,
    int* __restrict__ cmap, int* __restrict__ ntile, int* __restrict__ nvalid)
{
    const int bid = blockIdx.x;
    const int t = threadIdx.x;
    if (bid < 2048) {
        __shared__ __align__(16) unsigned short T[64][72];
        const int l0 = (bid & 31) * 64, d0 = ((bid >> 5) & 7) * 64, b = bid >> 8;
        const float* X = qin + ((size_t)b * ND + d0) * NL + l0;
        #pragma unroll
        for (int i = 0; i < 4; ++i) {
            int e = t + i * 256;
            int d = e >> 4, l4 = (e & 15) * 4;
            float4 v = *(const float4*)(X + (size_t)d * NL + l4);
            T[l4 + 0][d] = f2bf(v.x);
            T[l4 + 1][d] = f2bf(v.y);
            T[l4 + 2][d] = f2bf(v.z);
            T[l4 + 3][d] = f2bf(v.w);
        }
        __syncthreads();
        #pragma unroll
        for (int i = 0; i < 2; ++i) {
            int e = t + i * 256;
            int row = e >> 3, c8 = (e & 7) * 8;
            *(bf16x8*)(Xt + ((size_t)b * NL + l0 + row) * ND + d0 + c8) =
                *(const bf16x8*)&T[row][c8];
        }
    } else if (bid < 2432) {
        int idx = ((bid - 2048) * 256 + t) * 8;
        int o = idx >> 9, k = idx & 511;
        const float* src;
        float sc;
        if (o < 1024) { src = w_mem + (size_t)o * ND + k; sc = 1.0f; }
        else          { src = w_q + (size_t)(o - 1024) * ND + k;
                        sc = 0.125f * 1.4426950408889634f; }
        float4 f0 = *(const float4*)src;
        float4 f1 = *(const float4*)(src + 4);
        ushort4 p0 = { f2bf(f0.x * sc), f2bf(f0.y * sc), f2bf(f0.z * sc), f2bf(f0.w * sc) };
        ushort4 p1 = { f2bf(f1.x * sc), f2bf(f1.y * sc), f2bf(f1.z * sc), f2bf(f1.w * sc) };
        *(ushort4*)(Wc + idx) = p0;
        *(ushort4*)(Wc + idx + 4) = p1;
    } else {
        // ---- per-(batch,head) mask compaction ----
        __shared__ int wsum[4];
        const int sb = bid - 2432;
        const int b = sb >> 3, hh = sb & 7;
        const int lane = t & 63, wv = t >> 6;
        int4 ma = *(const int4*)&maskp[b * NL + t * 8];
        int4 mb = *(const int4*)&maskp[b * NL + t * 8 + 4];
        int m[8] = {ma.x, ma.y, ma.z, ma.w, mb.x, mb.y, mb.z, mb.w};
        int loc = 0;
        #pragma unroll
        for (int i = 0; i < 8; ++i) loc += m[i];
        int sc = loc;                         // wave inclusive scan
        #pragma unroll
        for (int off = 1; off < 64; off <<= 1) {
            int v = __shfl_up(sc, off);
            if (lane >= off) sc += v;
        }
        if (lane == 63) wsum[wv] = sc;
        __syncthreads();
        int wbase = 0;
        #pragma unroll
        for (int i = 0; i < 4; ++i) if (i < wv) wbase += wsum[i];
        int j = wbase + sc - loc;             // exclusive prefix for this group
        if (hh == 0) {
            int jj = j;
            #pragma unroll
            for (int i = 0; i < 8; ++i) {
                cmap[b * NL + t * 8 + i] = m[i] ? jj : -1;
                jj += m[i];
            }
        }
        const int nb = wsum[0] + wsum[1] + wsum[2] + wsum[3];
        const int Nt = (nb + 63) & ~63;
        if (hh == 0 && t == 0) { ntile[b] = Nt >> 6; nvalid[b] = nb; }
        const int pad = Nt - nb;
        for (int e = t; e < pad * 64; e += 256) {
            int jj = nb + (e >> 6), dd = e & 63;
            int slot = (jj & ~63) | perm64(jj & 63);
            Vt[(((size_t)(b * NH + hh)) * VROWS + dd) * NL + slot] = 0;
            Kh[(((size_t)(b * NH + hh)) * NL + jj) * NDH + dd] = 0;
        }
    }
}

// ---------------------------------------------------------------------------
// proj_mfma: C[o][l] = sum_k Wc[o][k] * Xt[b][l][k].
// EXACT R0/R4/R5/R6 version. Session-noise probe: identical code measured
// 48.9 / 62.0 / 50.4 / 51.1 us across sessions -- deltas <20% unmeasurable.
// ---------------------------------------------------------------------------
__global__ __launch_bounds__(256, 3) void proj_mfma(
    const unsigned short* __restrict__ Wc,
    const unsigned short* __restrict__ Xt,
    const int* __restrict__ cmap,
    unsigned short* __restrict__ Kh,
    unsigned short* __restrict__ Qh,
    unsigned short* __restrict__ Vt)
{
    __shared__ __align__(16) unsigned short As[128 * 64];
    __shared__ __align__(16) unsigned short Bs[128 * 64];

    const int b  = blockIdx.z;
    const int m0 = blockIdx.y * 128;
    const int n0 = blockIdx.x * 128;
    const int t  = threadIdx.x;
    const int w = t >> 6, lane = t & 63, quad = lane >> 4, lq = lane & 15;
    const int wo = (w >> 1) * 64, wl = (w & 1) * 64;
    const int lr = lane >> 3;
    const int cbsw = (lane & 7) ^ lr;
    const bool isV = (m0 >= 512) && (m0 < 1024);
    const f32x4 z4 = {0.f, 0.f, 0.f, 0.f};
    const int sw[2] = {(quad ^ (lq & 7)) * 8, ((4 + quad) ^ (lq & 7)) * 8};

    f32x4 acc[4][4];
    #pragma unroll
    for (int im = 0; im < 4; ++im)
        #pragma unroll
        for (int in = 0; in < 4; ++in) acc[im][in] = z4;

    if (!isV) {
        for (int k0 = 0; k0 < ND; k0 += 64) {
            __syncthreads();
            #pragma unroll 2
            for (int i = w; i < 32; i += 4) {
                if (i < 16) {
                    int R = i * 8;
                    async16(&As[R * 64],
                            Wc + (size_t)(m0 + R + lr) * ND + k0 + cbsw * 8);
                } else {
                    int R = (i - 16) * 8;
                    async16(&Bs[R * 64],
                            Xt + ((size_t)b * NL + n0 + R + lr) * ND + k0 + cbsw * 8);
                }
            }
            __syncthreads();
            #pragma unroll
            for (int ks = 0; ks < 2; ++ks) {
                bf16x8 af[4], bfr[4];
                #pragma unroll
                for (int im = 0; im < 4; ++im)
                    af[im] = *(const bf16x8*)&As[(wo + im * 16 + lq) * 64 + sw[ks]];
                #pragma unroll
                for (int in = 0; in < 4; ++in)
                    bfr[in] = *(const bf16x8*)&Bs[(wl + in * 16 + lq) * 64 + sw[ks]];
                #pragma unroll
                for (int im = 0; im < 4; ++im)
                    #pragma unroll
                    for (int in = 0; in < 4; ++in)
                        acc[im][in] = __builtin_amdgcn_mfma_f32_16x16x32_bf16(
                            af[im], bfr[in], acc[im][in], 0, 0, 0);
            }
        }
        if (m0 < 512) {
            // K region: compacted rows
            int j[4];
            #pragma unroll
            for (int in = 0; in < 4; ++in)
                j[in] = cmap[b * NL + n0 + wl + in * 16 + lq];
            #pragma unroll
            for (int im = 0; im < 4; ++im) {
                int o  = (m0 + wo + im * 16 + quad * 4) & 511;
                int hh = o >> 6, dh = o & 63;
                #pragma unroll
                for (int in = 0; in < 4; ++in) {
                    if (j[in] >= 0) {
                        ushort4 pk = { f2bf(acc[im][in][0]), f2bf(acc[im][in][1]),
                                       f2bf(acc[im][in][2]), f2bf(acc[im][in][3]) };
                        *(ushort4*)&Kh[(((size_t)b * NH + hh) * NL + j[in]) * NDH + dh] = pk;
                    }
                }
            }
        } else {
            // Q region: unchanged
            #pragma unroll
            for (int im = 0; im < 4; ++im) {
                int o  = (m0 + wo + im * 16 + quad * 4) & 511;
                int hh = o >> 6, dh = o & 63;
                #pragma unroll
                for (int in = 0; in < 4; ++in) {
                    int l = n0 + wl + in * 16 + lq;
                    ushort4 pk = { f2bf(acc[im][in][0]), f2bf(acc[im][in][1]),
                                   f2bf(acc[im][in][2]), f2bf(acc[im][in][3]) };
                    *(ushort4*)&Qh[(((size_t)b * NH + hh) * NL + l) * NDH + dh] = pk;
                }
            }
        }
    } else {
        for (int k0 = 0; k0 < ND; k0 += 64) {
            __syncthreads();
            #pragma unroll 2
            for (int i = w; i < 32; i += 4) {
                if (i < 16) {
                    int R = i * 8;
                    async16(&As[R * 64],
                            Wc + (size_t)(m0 + R + lr) * ND + k0 + cbsw * 8);
                } else {
                    int R = (i - 16) * 8;
                    async16(&Bs[R * 64],
                            Xt + ((size_t)b * NL + n0 + R + lr) * ND + k0 + cbsw * 8);
                }
            }
            __syncthreads();
            #pragma unroll
            for (int ks = 0; ks < 2; ++ks) {
                bf16x8 af[4], bfr[4];
                #pragma unroll
                for (int im = 0; im < 4; ++im)
                    af[im] = *(const bf16x8*)&As[(wo + im * 16 + lq) * 64 + sw[ks]];
                #pragma unroll
                for (int in = 0; in < 4; ++in)
                    bfr[in] = *(const bf16x8*)&Bs[(wl + in * 16 + lq) * 64 + sw[ks]];
                // swapped: acc[im = l-subtile][in = dh-subtile]
                #pragma unroll
                for (int im = 0; im < 4; ++im)
                    #pragma unroll
                    for (int in = 0; in < 4; ++in)
                        acc[im][in] = __builtin_amdgcn_mfma_f32_16x16x32_bf16(
                            bfr[im], af[in], acc[im][in], 0, 0, 0);
            }
        }
        // V region: compacted + key-permuted scalar scatter
        #pragma unroll
        for (int im = 0; im < 4; ++im) {
            int l4 = n0 + wl + im * 16 + quad * 4;      // 4 consecutive l
            int4 j4 = *(const int4*)&cmap[b * NL + l4];
            int jj[4] = {j4.x, j4.y, j4.z, j4.w};
            int slot[4];
            #pragma unroll
            for (int r = 0; r < 4; ++r)
                slot[r] = (jj[r] & ~63) | perm64(jj[r] & 63);
            #pragma unroll
            for (int in = 0; in < 4; ++in) {
                int o  = m0 - 512 + wo + in * 16 + lq;  // 0..511
                int hh = o >> 6, dd = o & 63;
                const size_t rowbase = (((size_t)(b * NH + hh)) * VROWS + dd) * NL;
                #pragma unroll
                for (int r = 0; r < 4; ++r)
                    if (jj[r] >= 0)
                        Vt[rowbase + slot[r]] = f2bf(acc[im][in][r]);
            }
        }
    }
}

// ---------------------------------------------------------------------------
// attn_mfma: back to the R5 geometry -- 512-thread blocks (8 waves x 32
// q-rows = 256-row q-tile), grid 512 = 2 blocks/CU, 16 waves/CU (4/SIMD:
// R6 showed 2/SIMD with 2x reuse is exactly neutral -> latency-bound, so
// prefer the wave-rich shape for arbitration). KVBLK=128 mega-tiles +
// f32 pre-pack lsum retained. NEW: s_setprio(1) around the QK and PV MFMA
// clusters (T5): with 8 waves drifting between per-mega-tile barriers,
// MFMA-ready waves now preempt memory/VALU-issuing waves on the SIMD.
// Math is bit-identical to R5/R6.
// ---------------------------------------------------------------------------
__global__ __launch_bounds__(512, 4) void attn_mfma(
    const unsigned short* __restrict__ Qh,
    const unsigned short* __restrict__ Kh,
    const unsigned short* __restrict__ Vt,
    const int* __restrict__ ntilep,
    const int* __restrict__ nvalidp,
    float* __restrict__ out)
{
    __shared__ __align__(16) unsigned short Ks2[2][2 * 64 * 64];  // 2 x 16 KB
    __shared__ __align__(16) unsigned short Vs2[2][2 * 64 * 64];  // 2 x 16 KB

    const int id = blockIdx.x;
    const int h  = id & 7;                 // XCD swizzle: same h -> same XCD
    const int b  = (id >> 3) & 7;
    const int q0 = (id >> 6) * 256;
    const int t = threadIdx.x;             // 0..511
    const int w = t >> 6;                  // 0..7
    const int lane = t & 63, quad = lane >> 4, lq = lane & 15;
    const int lr = lane >> 3;
    const int cbsw = (lane & 7) ^ lr;
    const f32x4 z4 = {0.f, 0.f, 0.f, 0.f};

    const unsigned short* Qg = Qh + ((size_t)(b * NH + h)) * NL * NDH;
    const unsigned short* Kg = Kh + ((size_t)(b * NH + h)) * NL * NDH;
    const unsigned short* Vg = Vt + ((size_t)(b * NH + h)) * VROWS * NL;
    const int ntiles = ntilep[b];

    const int sw0 = (quad ^ (lq & 7)) * 8;
    const int sw1 = ((4 + quad) ^ (lq & 7)) * 8;

    // wave w stages K rows 8w..8w+7 and V rows 8w..8w+7 of each half
    const unsigned short* kgp = Kg + (size_t)(w * 8 + lr) * NDH + cbsw * 8;
    const unsigned short* vgp = Vg + (size_t)(w * 8 + lr) * NL + cbsw * 8;

    // stage a 128-key mega-tile (halves at +0 and +4096 ushorts)
    auto stage128 = [&](unsigned short* Kd, unsigned short* Vd, int kn) {
        async16(Kd + w * 512,        kgp + (size_t)kn * NDH);
        async16(Kd + 4096 + w * 512, kgp + (size_t)(kn + 64) * NDH);
        async16(Vd + w * 512,        vgp + kn);
        async16(Vd + 4096 + w * 512, vgp + kn + 64);
    };

    // ---- stage mega-tile 0; Q fragments straight to registers meanwhile ----
    stage128(Ks2[0], Vs2[0], 0);

    bf16x8 qf[2][2];
    #pragma unroll
    for (int ni = 0; ni < 2; ++ni)
        #pragma unroll
        for (int ks = 0; ks < 2; ++ks)
            qf[ni][ks] = *(const bf16x8*)
                &Qg[(size_t)(q0 + w * 32 + ni * 16 + lq) * NDH + ks * 32 + quad * 8];

    f32x4 oacc[4][2];
    #pragma unroll
    for (int dm = 0; dm < 4; ++dm)
        #pragma unroll
        for (int ni = 0; ni < 2; ++ni) oacc[dm][ni] = z4;
    float ls[2] = {0.f, 0.f};   // per-lane partial row-sums of p (f32)

    // one 64-key sub-body on (KsB, VsB)
    auto sub = [&](const unsigned short* KsB, const unsigned short* VsB) {
        const unsigned short* kb0 = KsB + lq * 64 + sw0;
        const unsigned short* kb1 = KsB + lq * 64 + sw1;
        const unsigned short* vb0 = VsB + lq * 64 + sw0;
        const unsigned short* vb1 = VsB + lq * 64 + sw1;

        // ---- S^T = K Q^T (log2 units); first k-step assigns ----
        f32x4 sacc[4][2];
        __builtin_amdgcn_s_setprio(1);
        #pragma unroll
        for (int mi = 0; mi < 4; ++mi) {
            bf16x8 kf = *(const bf16x8*)&kb0[mi * 1024];
            sacc[mi][0] = __builtin_amdgcn_mfma_f32_16x16x32_bf16(kf, qf[0][0], z4, 0, 0, 0);
            sacc[mi][1] = __builtin_amdgcn_mfma_f32_16x16x32_bf16(kf, qf[1][0], z4, 0, 0, 0);
        }
        #pragma unroll
        for (int mi = 0; mi < 4; ++mi) {
            bf16x8 kf = *(const bf16x8*)&kb1[mi * 1024];
            sacc[mi][0] = __builtin_amdgcn_mfma_f32_16x16x32_bf16(kf, qf[0][1], sacc[mi][0], 0, 0, 0);
            sacc[mi][1] = __builtin_amdgcn_mfma_f32_16x16x32_bf16(kf, qf[1][1], sacc[mi][1], 0, 0, 0);
        }
        __builtin_amdgcn_s_setprio(0);

        // ---- per ks-half: p = exp2(s), f32 presum, pack, PV MFMA ----
        #pragma unroll
        for (int ks = 0; ks < 2; ++ks) {
            u32x4 pfu[2];
            #pragma unroll
            for (int half = 0; half < 2; ++half) {
                const int mi = ks * 2 + half, jp = half * 2;
                #pragma unroll
                for (int ni = 0; ni < 2; ++ni) {
                    float e0 = exp2_fast(sacc[mi][ni][0]);
                    float e1 = exp2_fast(sacc[mi][ni][1]);
                    float e2 = exp2_fast(sacc[mi][ni][2]);
                    float e3 = exp2_fast(sacc[mi][ni][3]);
                    ls[ni] += (e0 + e1) + (e2 + e3);
                    pfu[ni][jp + 0] = pack_bf16(e0, e1);
                    pfu[ni][jp + 1] = pack_bf16(e2, e3);
                }
            }
            const unsigned short* vb = ks ? vb1 : vb0;
            __builtin_amdgcn_s_setprio(1);
            #pragma unroll
            for (int dm = 0; dm < 4; ++dm) {
                bf16x8 vf = *(const bf16x8*)&vb[dm * 1024];
                oacc[dm][0] = __builtin_amdgcn_mfma_f32_16x16x32_bf16(
                    vf, __builtin_bit_cast(bf16x8, pfu[0]), oacc[dm][0], 0, 0, 0);
                oacc[dm][1] = __builtin_amdgcn_mfma_f32_16x16x32_bf16(
                    vf, __builtin_bit_cast(bf16x8, pfu[1]), oacc[dm][1], 0, 0, 0);
            }
            __builtin_amdgcn_s_setprio(0);
        }
    };

    const int npairs = ntiles >> 1, odd = ntiles & 1;
    int p = 0;
    #pragma unroll 1
    for (; p + 1 < npairs; ++p) {
        const int cb = p & 1;
        __syncthreads();          // drains DMA for buf cb; frees buf cb^1
        stage128(Ks2[cb ^ 1], Vs2[cb ^ 1], (p + 1) * 128);
        sub(Ks2[cb], Vs2[cb]);
        sub(Ks2[cb] + 4096, Vs2[cb] + 4096);
    }
    if (npairs > 0) {             // last full pair; prefetch odd tail if any
        const int cb = p & 1;
        __syncthreads();
        if (odd) stage128(Ks2[cb ^ 1], Vs2[cb ^ 1], npairs * 128);
        sub(Ks2[cb], Vs2[cb]);
        sub(Ks2[cb] + 4096, Vs2[cb] + 4096);
        ++p;
    }
    if (odd) {                    // tail: half 0 of the last-staged buffer
        const int cb = p & 1;
        __syncthreads();
        sub(Ks2[cb], Vs2[cb]);
    }

    // ---- epilogue: reduce ls across the 4 quads; subtract exact pad ----
    const float padc = (float)(ntiles * 64 - nvalidp[b]);
    float inv[2];
    #pragma unroll
    for (int ni = 0; ni < 2; ++ni) {
        float s = ls[ni];
        s += __shfl_xor(s, 16);
        s += __shfl_xor(s, 32);
        inv[ni] = 1.0f / (s - padc);
    }

    #pragma unroll
    for (int dm = 0; dm < 4; ++dm)
        #pragma unroll
        for (int ni = 0; ni < 2; ++ni)
            #pragma unroll
            for (int r = 0; r < 4; ++r) {
                int dh = dm * 16 + quad * 4 + r;
                int l  = q0 + w * 32 + ni * 16 + lq;
                out[((size_t)b * ND + h * NDH + dh) * NL + l] =
                    oacc[dm][ni][r] * inv[ni];
            }
}

extern "C" void kernel_launch(void* const* d_in, const int* in_sizes, int n_in,
                              void* d_out, int out_size, void* d_ws, size_t ws_size,
                              hipStream_t stream) {
    const float* queries = (const float*)d_in[0];
    const int*   maskp   = (const int*)d_in[1];
    const float* w_mem   = (const float*)d_in[2];
    const float* w_q     = (const float*)d_in[3];
    float* out = (float*)d_out;

    const size_t headElems  = (size_t)NB * NH * NL * NDH;    // 8.39M
    const size_t vElems     = (size_t)NB * NH * VROWS * NL;  // 9.44M
    unsigned short* Kh = (unsigned short*)d_ws;
    unsigned short* Vt = Kh + headElems;
    unsigned short* Qh = Vt + vElems;
    unsigned short* Wc = Qh + headElems;                     // 1536*512
    unsigned short* Xt = Wc + (size_t)1536 * ND;             // 8*2048*512
    int* cmap   = (int*)(Xt + (size_t)NB * NL * ND);         // 8*2048 ints
    int* ntile  = cmap + NB * NL;                            // 8 ints
    int* nvalid = ntile + NB;                                // 8 ints
    // total ws use: ~71 MB

    prep<<<2496, 256, 0, stream>>>(queries, w_mem, w_q, maskp,
                                   Xt, Wc, Vt, Kh, cmap, ntile, nvalid);

    dim3 g1(NL / 128, 1536 / 128, NB); // (16, 12, 8)
    proj_mfma<<<g1, 256, 0, stream>>>(Wc, Xt, cmap, Kh, Qh, Vt);

    attn_mfma<<<512, 512, 0, stream>>>(Qh, Kh, Vt, ntile, nvalid, out);
}